// Round 1
// 1650.610 us; speedup vs baseline: 1.0864x; 1.0864x over previous
//
#include <hip/hip_runtime.h>
#include <hip/hip_fp16.h>
#include <math.h>

#define Nn 50000
#define Ff 16
#define Tt 12
#define Hh 64
#define Ee 1600000
#define Cc 80  // F + H

typedef _Float16 f16x8 __attribute__((ext_vector_type(8)));
typedef float f32x4 __attribute__((ext_vector_type(4)));

static __device__ __forceinline__ float sigmoidf_(float x) { return 1.0f / (1.0f + expf(-x)); }

// ---------------- CSR build ----------------
// dc[d] accumulates (count << 42) + round(ew * 2^21) in one u64 atomic.
__global__ void k_deg(const int* __restrict__ ei, const float* __restrict__ ew,
                      unsigned long long* __restrict__ dc) {
  int e = blockIdx.x * blockDim.x + threadIdx.x;
  if (e >= Ee) return;
  int d = ei[Ee + e];
  unsigned long long pk = (1ULL << 42) + (unsigned long long)(ew[e] * 2097152.0f + 0.5f);
  atomicAdd(&dc[d], pk);
}

__global__ void k_dis(const unsigned long long* __restrict__ dc,
                      float* __restrict__ dis, int* __restrict__ cnt) {
  int i = blockIdx.x * blockDim.x + threadIdx.x;
  if (i >= Nn) return;
  unsigned long long v = dc[i];
  cnt[i] = (int)(v >> 42);
  float deg = (float)(v & ((1ULL << 42) - 1)) * (1.0f / 2097152.0f);
  dis[i] = 1.0f / sqrtf(deg + 1.0f);
}

__global__ __launch_bounds__(1024) void k_scan(const int* __restrict__ cnt,
                                               int* __restrict__ rp, int* __restrict__ cur) {
  __shared__ int ss[1024];
  const int ITEMS = (Nn + 1023) / 1024;  // 49
  int t = threadIdx.x;
  int base = t * ITEMS;
  int sum = 0;
  for (int k = 0; k < ITEMS; k++) {
    int idx = base + k;
    if (idx < Nn) sum += cnt[idx];
  }
  ss[t] = sum;
  __syncthreads();
  for (int off = 1; off < 1024; off <<= 1) {
    int v = (t >= off) ? ss[t - off] : 0;
    __syncthreads();
    ss[t] += v;
    __syncthreads();
  }
  int run = ss[t] - sum;  // exclusive prefix
  for (int k = 0; k < ITEMS; k++) {
    int idx = base + k;
    if (idx < Nn) { rp[idx] = run; cur[idx] = run; run += cnt[idx]; }
  }
  if (t == 0) rp[Nn] = Ee;
}

// edge2[pos] = {src, normalized weight}: one scattered 8-B store per edge
__global__ void k_scatter(const int* __restrict__ ei, const float* __restrict__ ew,
                          const float* __restrict__ dis, int* __restrict__ cur,
                          int2* __restrict__ edge2) {
  int e = blockIdx.x * blockDim.x + threadIdx.x;
  if (e >= Ee) return;
  int s = ei[e];
  int d = ei[Ee + e];
  float w = ew[e] * dis[s] * dis[d];
  int pos = atomicAdd(&cur[d], 1);
  edge2[pos] = make_int2(s, __float_as_int(w));
}

// ---------------- x fp32 -> fp16 (once) ----------------
__global__ void k_cvt_x(const float* __restrict__ x, __half* __restrict__ x16) {
  size_t idx = (size_t)blockIdx.x * blockDim.x + threadIdx.x;
  const size_t total = (size_t)Nn * Ff * Tt;
  if (idx < total) x16[idx] = __float2half(x[idx]);
}

// ---------------- weight fragments for MFMA (once) ----------------
// slot s: 0-3 = Wz tiles, 4-7 = Wr tiles, 8-11 = Wh tiles; n0 = (s&3)*16.
// frag[((s*3+ks)*64 + lane)*8 + j] = W[k][n0 + (lane&15)], k = ks*32 + (lane>>4)*8 + j (0 if k>=80)
__global__ void k_wfrag(const float* __restrict__ Wz, const float* __restrict__ Wr,
                        const float* __restrict__ Wh, __half* __restrict__ frag) {
  int t = blockIdx.x * 256 + threadIdx.x;
  if (t >= 12 * 3 * 64) return;
  int s = t / 192, rem = t % 192, ks = rem / 64, lane = rem % 64;
  int q = lane >> 4, nl = lane & 15;
  const float* W = (s < 4) ? Wz : (s < 8) ? Wr : Wh;
  int n0 = (s & 3) * 16;
  __half tmp[8];
#pragma unroll
  for (int j = 0; j < 8; j++) {
    int k = ks * 32 + q * 8 + j;
    float v = (k < Cc) ? W[k * Hh + n0 + nl] : 0.f;
    tmp[j] = __float2half(v);
  }
  *(uint4*)(frag + ((size_t)(s * 3 + ks) * 64 + lane) * 8) = *(uint4*)tmp;
}

// Wa (64x64) fragments for attention MFMA (once).
// slot s (0..7): tile = s>>1 (n0 = tile*16), ks = s&1 (k0 = ks*32).
// fragA[(s*64 + lane)*8 + j] = Wa[k0 + (lane>>4)*8 + j][n0 + (lane&15)]
__global__ void k_wfrag_a(const float* __restrict__ Wa, __half* __restrict__ fragA) {
  int t = blockIdx.x * 256 + threadIdx.x;
  if (t >= 8 * 64) return;
  int s = t >> 6, lane = t & 63;
  int tile = s >> 1, ks = s & 1;
  int q = lane >> 4, m = lane & 15;
  __half tmp[8];
#pragma unroll
  for (int j = 0; j < 8; j++) {
    int k = ks * 32 + q * 8 + j;
    tmp[j] = __float2half(Wa[k * Hh + tile * 16 + m]);
  }
  *(uint4*)(fragA + ((size_t)t) * 8) = *(uint4*)tmp;
}

// ---------------- Px16[t][i][f] = (A_hat @ x): wave per node, 48 lanes x 8B per edge ----------------
__global__ __launch_bounds__(256) void k_agg_px(
    const float* __restrict__ x, const __half* __restrict__ x16, __half* __restrict__ Px16,
    const int* __restrict__ rp, const int2* __restrict__ edge2,
    const float* __restrict__ dis) {
  int i = blockIdx.x * 4 + (threadIdx.x >> 6);
  if (i >= Nn) return;
  int lane = threadIdx.x & 63;
  const int R = Ff * Tt;  // 192
  const bool act = lane < 48;
  float d = dis[i], sn = d * d;
  float a0 = 0.f, a1 = 0.f, a2 = 0.f, a3 = 0.f;
  if (act) {
    float4 sv = *(const float4*)(x + (size_t)i * R + 4 * lane);  // self, fp32 exact
    a0 = sn * sv.x; a1 = sn * sv.y; a2 = sn * sv.z; a3 = sn * sv.w;
  }
  int jb = rp[i], je = rp[i + 1];
  for (int j = jb; j < je; j += 2) {
    int jc1 = min(j + 1, Ee - 1);
    int2 e0 = edge2[j];
    int2 e1 = edge2[jc1];
    float w0 = __int_as_float(e0.y);
    float w1 = (j + 1 < je) ? __int_as_float(e1.y) : 0.f;
    if (act) {
      uint2 g0 = *(const uint2*)(x16 + (size_t)e0.x * R + 4 * lane);
      uint2 g1 = *(const uint2*)(x16 + (size_t)e1.x * R + 4 * lane);
      float2 p01 = __half22float2(*reinterpret_cast<const __half2*>(&g0.x));
      float2 p23 = __half22float2(*reinterpret_cast<const __half2*>(&g0.y));
      float2 q01 = __half22float2(*reinterpret_cast<const __half2*>(&g1.x));
      float2 q23 = __half22float2(*reinterpret_cast<const __half2*>(&g1.y));
      a0 = fmaf(w0, p01.x, a0); a1 = fmaf(w0, p01.y, a1);
      a2 = fmaf(w0, p23.x, a2); a3 = fmaf(w0, p23.y, a3);
      a0 = fmaf(w1, q01.x, a0); a1 = fmaf(w1, q01.y, a1);
      a2 = fmaf(w1, q23.x, a2); a3 = fmaf(w1, q23.y, a3);
    }
  }
  if (act) {
#pragma unroll
    for (int k = 0; k < 4; k++) {
      int cch = 4 * lane + k;           // channel = f*T + t
      int f = cch / Tt, tt = cch % Tt;
      float val = (k == 0) ? a0 : (k == 1) ? a1 : (k == 2) ? a2 : a3;
      Px16[(size_t)tt * Nn * Ff + (size_t)i * Ff + f] = __float2half(val);
    }
  }
}

// ---------------- aggregation: wave per node, 16 lanes/edge x 8B, 16 edges/iteration ----------------
__global__ __launch_bounds__(256) void k_agg64v(
    const __half* __restrict__ v, __half* __restrict__ outv,
    const int* __restrict__ rp, const int2* __restrict__ edge2,
    const float* __restrict__ dis) {
  int i = blockIdx.x * 4 + (threadIdx.x >> 6);
  if (i >= Nn) return;
  int lane = threadIdx.x & 63;
  int g = lane >> 4;   // edge slot 0..3
  int c = lane & 15;   // channel quad: 4c..4c+3
  float d = dis[i], sn = d * d;
  float a0, a1, a2, a3;
  {
    const uint2 gv = *(const uint2*)(v + (size_t)i * Hh + 4 * c);  // self
    float2 f01 = __half22float2(*reinterpret_cast<const __half2*>(&gv.x));
    float2 f23 = __half22float2(*reinterpret_cast<const __half2*>(&gv.y));
    float ws = (g == 0) ? sn : 0.f;
    a0 = ws * f01.x; a1 = ws * f01.y; a2 = ws * f23.x; a3 = ws * f23.y;
  }
  int jb = rp[i], je = rp[i + 1];
  for (int j0 = jb; j0 < je; j0 += 16) {
    int j1 = j0 + g;
    int j2 = j0 + 4 + g;
    int j3 = j0 + 8 + g;
    int j4 = j0 + 12 + g;
    int2 e1 = edge2[min(j1, Ee - 1)];
    int2 e2 = edge2[min(j2, Ee - 1)];
    int2 e3 = edge2[min(j3, Ee - 1)];
    int2 e4 = edge2[min(j4, Ee - 1)];
    float w1 = (j1 < je) ? __int_as_float(e1.y) : 0.f;
    float w2 = (j2 < je) ? __int_as_float(e2.y) : 0.f;
    float w3 = (j3 < je) ? __int_as_float(e3.y) : 0.f;
    float w4 = (j4 < je) ? __int_as_float(e4.y) : 0.f;
    const uint2 g1 = *(const uint2*)(v + (size_t)e1.x * Hh + 4 * c);
    const uint2 g2 = *(const uint2*)(v + (size_t)e2.x * Hh + 4 * c);
    const uint2 g3 = *(const uint2*)(v + (size_t)e3.x * Hh + 4 * c);
    const uint2 g4 = *(const uint2*)(v + (size_t)e4.x * Hh + 4 * c);
    float2 p01 = __half22float2(*reinterpret_cast<const __half2*>(&g1.x));
    float2 p23 = __half22float2(*reinterpret_cast<const __half2*>(&g1.y));
    float2 q01 = __half22float2(*reinterpret_cast<const __half2*>(&g2.x));
    float2 q23 = __half22float2(*reinterpret_cast<const __half2*>(&g2.y));
    float2 r01 = __half22float2(*reinterpret_cast<const __half2*>(&g3.x));
    float2 r23 = __half22float2(*reinterpret_cast<const __half2*>(&g3.y));
    float2 s01 = __half22float2(*reinterpret_cast<const __half2*>(&g4.x));
    float2 s23 = __half22float2(*reinterpret_cast<const __half2*>(&g4.y));
    a0 = fmaf(w1, p01.x, a0); a1 = fmaf(w1, p01.y, a1);
    a2 = fmaf(w1, p23.x, a2); a3 = fmaf(w1, p23.y, a3);
    a0 = fmaf(w2, q01.x, a0); a1 = fmaf(w2, q01.y, a1);
    a2 = fmaf(w2, q23.x, a2); a3 = fmaf(w2, q23.y, a3);
    a0 = fmaf(w3, r01.x, a0); a1 = fmaf(w3, r01.y, a1);
    a2 = fmaf(w3, r23.x, a2); a3 = fmaf(w3, r23.y, a3);
    a0 = fmaf(w4, s01.x, a0); a1 = fmaf(w4, s01.y, a1);
    a2 = fmaf(w4, s23.x, a2); a3 = fmaf(w4, s23.y, a3);
  }
  a0 += __shfl_xor(a0, 16, 64); a1 += __shfl_xor(a1, 16, 64);
  a2 += __shfl_xor(a2, 16, 64); a3 += __shfl_xor(a3, 16, 64);
  a0 += __shfl_xor(a0, 32, 64); a1 += __shfl_xor(a1, 32, 64);
  a2 += __shfl_xor(a2, 32, 64); a3 += __shfl_xor(a3, 32, 64);
  if (lane < 16) {
    __half2 h01, h23;
    h01.x = __float2half_rn(a0); h01.y = __float2half_rn(a1);
    h23.x = __float2half_rn(a2); h23.y = __float2half_rn(a3);
    uint2 st;
    st.x = *reinterpret_cast<unsigned int*>(&h01);
    st.y = *reinterpret_cast<unsigned int*>(&h23);
    *(uint2*)(outv + (size_t)i * Hh + 4 * c) = st;
  }
}

// ---- shared fp16 staging: 16 nodes x 104 halves (row = [Px(16) | P64(64) | zeros(24)]) ----
// Row stride 104 halves (208 B): a_frag ds_read_b128 lands 2 lanes/bank (free).
static __device__ __forceinline__ void stage_x16(
    __half* sX16, const __half* __restrict__ Px16t, const __half* __restrict__ P64,
    int i0, int tid) {
  if (tid < 160) {
    int n = tid / 10, r = tid % 10;
    int i = i0 + n;
    uint4 raw = (r < 2) ? *(const uint4*)(Px16t + (size_t)i * Ff + r * 8)
                        : *(const uint4*)(P64 + (size_t)i * Hh + (r - 2) * 8);
    *(uint4*)(sX16 + n * 104 + r * 8) = raw;
  } else if (tid < 208) {
    int p = tid - 160, n = p / 3, part = p % 3;
    *(uint4*)(sX16 + n * 104 + 80 + part * 8) = make_uint4(0u, 0u, 0u, 0u);
  }
}

// ---------------- GEMM z/r via MFMA 16x16x32 f16: block = 16 nodes, wave w -> out tile w ----------------
// A: X[node][c] (LDS, fp16). B: weight frags (global, pre-swizzled). K = 80 padded to 96 (3 MFMA).
// Layouts [verified per guide m89/m120]: A[m=lane&15][k=(lane>>4)*8+j]; C/D col=lane&15, row=(lane>>4)*4+reg.
// NOTE: no waves-per-EU hint (2nd __launch_bounds__ arg => scratch spill disaster, r2/r6).
__global__ __launch_bounds__(256) void k_gemm_zr(
    const __half* __restrict__ Px16, const __half* __restrict__ Ph16,
    const __half* __restrict__ h16, const __half* __restrict__ frag,
    const float* __restrict__ bz, const float* __restrict__ br,
    __half* __restrict__ zb16, __half* __restrict__ rh16, int tstep) {
  __shared__ __align__(16) __half sX16[16 * 104];
  const int tid = threadIdx.x;
  const int i0 = blockIdx.x * 16;  // Nn = 3125*16 exactly, no guards
  const int wv = tid >> 6, lane = tid & 63;
  // b-fragments: z = slot wv, r = slot 4+wv (coalesced b128 loads, L2-resident)
  f16x8 bzf[3], brf[3];
#pragma unroll
  for (int ks = 0; ks < 3; ks++) {
    bzf[ks] = *(const f16x8*)(frag + ((size_t)(wv * 3 + ks) * 64 + lane) * 8);
    brf[ks] = *(const f16x8*)(frag + ((size_t)((4 + wv) * 3 + ks) * 64 + lane) * 8);
  }
  stage_x16(sX16, Px16 + (size_t)tstep * Nn * Ff, Ph16, i0, tid);
  __syncthreads();
  const int m = lane & 15, q = lane >> 4;
  f32x4 accz = {0.f, 0.f, 0.f, 0.f}, accr = {0.f, 0.f, 0.f, 0.f};
#pragma unroll
  for (int ks = 0; ks < 3; ks++) {
    f16x8 a = *(const f16x8*)(sX16 + m * 104 + ks * 32 + q * 8);
    accz = __builtin_amdgcn_mfma_f32_16x16x32_f16(a, bzf[ks], accz, 0, 0, 0);
    accr = __builtin_amdgcn_mfma_f32_16x16x32_f16(a, brf[ks], accr, 0, 0, 0);
  }
  const int o = wv * 16 + m;
  float bzo = bz[o], bro = br[o];
  const int nb = i0 + q * 4;
#pragma unroll
  for (int r = 0; r < 4; r++) {
    int node = nb + r;
    float zv = sigmoidf_(accz[r] + bzo);
    float rv = sigmoidf_(accr[r] + bro);
    float hv = __half2float(h16[(size_t)node * Hh + o]);
    zb16[(size_t)node * Hh + o] = __float2half(zv);
    rh16[(size_t)node * Hh + o] = __float2half(rv * hv);
  }
}

// ---------------- GEMM h via MFMA + GRU update: wave w -> out tile w (slot 8+w) ----------------
__global__ __launch_bounds__(256) void k_gemm_h(
    const __half* __restrict__ Px16, const __half* __restrict__ Prh16,
    const __half* __restrict__ zb16, float* __restrict__ h, __half* __restrict__ h16,
    __half* __restrict__ hs16, const __half* __restrict__ frag,
    const float* __restrict__ bh, int tstep) {
  __shared__ __align__(16) __half sX16[16 * 104];
  const int tid = threadIdx.x;
  const int i0 = blockIdx.x * 16;
  const int wv = tid >> 6, lane = tid & 63;
  f16x8 bf[3];
#pragma unroll
  for (int ks = 0; ks < 3; ks++)
    bf[ks] = *(const f16x8*)(frag + ((size_t)((8 + wv) * 3 + ks) * 64 + lane) * 8);
  stage_x16(sX16, Px16 + (size_t)tstep * Nn * Ff, Prh16, i0, tid);
  __syncthreads();
  const int m = lane & 15, q = lane >> 4;
  f32x4 acc = {0.f, 0.f, 0.f, 0.f};
#pragma unroll
  for (int ks = 0; ks < 3; ks++) {
    f16x8 a = *(const f16x8*)(sX16 + m * 104 + ks * 32 + q * 8);
    acc = __builtin_amdgcn_mfma_f32_16x16x32_f16(a, bf[ks], acc, 0, 0, 0);
  }
  const int o = wv * 16 + m;
  float bho = bh[o];
  const int nb = i0 + q * 4;
  __half* hst = hs16 + (size_t)tstep * Nn * Hh;
#pragma unroll
  for (int r = 0; r < 4; r++) {
    int node = nb + r;
    float hc = tanhf(acc[r] + bho);
    float zv = __half2float(zb16[(size_t)node * Hh + o]);
    float hv = h[(size_t)node * Hh + o];
    float hn = zv * hv + (1.0f - zv) * hc;
    h[(size_t)node * Hh + o] = hn;
    __half hh = __float2half(hn);
    h16[(size_t)node * Hh + o] = hh;
    hst[(size_t)node * Hh + o] = hh;
  }
}

// ---------------- attention + output via MFMA: wave per node ----------------
// score = tanh(hs[12x64] @ Wa[64x64] + ba) computed with 8x mfma_f32_16x16x32_f16.
// A-frag: row m = t (m>=12 clamped to row 11, results discarded); k = ks*32 + q*8 + j.
// D layout [m89]: col o = tile*16 + (lane&15), row t = (lane>>4)*4 + r.
// No LDS at all; Wa frags pre-swizzled by k_wfrag_a (L2-resident, 8 KB).
__global__ __launch_bounds__(256) void k_att(
    const __half* __restrict__ hs16, const __half* __restrict__ fragA,
    const float* __restrict__ ba, const float* __restrict__ cv,
    const float* __restrict__ Wfc, const float* __restrict__ bfc,
    float* __restrict__ out) {
  const int tid = threadIdx.x;
  const int wv = tid >> 6, lane = tid & 63;
  const int i = blockIdx.x * 4 + wv;
  if (i >= Nn) return;
  const int m = lane & 15, q = lane >> 4;

  // B fragments: 8 slots (4 col-tiles x 2 K-steps), identical across waves -> L2 hits
  f16x8 bf[4][2];
#pragma unroll
  for (int s = 0; s < 8; s++)
    bf[s >> 1][s & 1] = *(const f16x8*)(fragA + (size_t)(s * 64 + lane) * 8);

  // A fragments: hs rows for this node (t = m, clamped; garbage rows only affect discarded D rows)
  const int tm = (m < Tt) ? m : (Tt - 1);
  const __half* hbase = hs16 + (size_t)tm * Nn * Hh + (size_t)i * Hh;
  f16x8 a0 = *(const f16x8*)(hbase + q * 8);
  f16x8 a1 = *(const f16x8*)(hbase + 32 + q * 8);

  f32x4 acc[4];
#pragma unroll
  for (int tile = 0; tile < 4; tile++) acc[tile] = f32x4{0.f, 0.f, 0.f, 0.f};
#pragma unroll
  for (int tile = 0; tile < 4; tile++) {
    acc[tile] = __builtin_amdgcn_mfma_f32_16x16x32_f16(a0, bf[tile][0], acc[tile], 0, 0, 0);
    acc[tile] = __builtin_amdgcn_mfma_f32_16x16x32_f16(a1, bf[tile][1], acc[tile], 0, 0, 0);
  }

  // epilogue: lane holds score[t = q*4+r][o = tile*16+m]
  float ba_l[4], cv_l[4];
#pragma unroll
  for (int tile = 0; tile < 4; tile++) {
    ba_l[tile] = ba[tile * 16 + m];
    cv_l[tile] = cv[tile * 16 + m];
  }
  float ar[4];
#pragma unroll
  for (int r = 0; r < 4; r++) {
    float s = 0.f;
#pragma unroll
    for (int tile = 0; tile < 4; tile++)
      s += tanhf(acc[tile][r] + ba_l[tile]) * cv_l[tile];
    // reduce over the 16 lanes of this q-group (covers all 64 o's)
    s += __shfl_xor(s, 1, 64);
    s += __shfl_xor(s, 2, 64);
    s += __shfl_xor(s, 4, 64);
    s += __shfl_xor(s, 8, 64);
    ar[r] = s;  // align[q*4 + r], valid for q*4+r < 12
  }
  // broadcast all 12 align values to every lane
  float al[Tt];
#pragma unroll
  for (int t = 0; t < Tt; t++) al[t] = __shfl(ar[t & 3], (t >> 2) * 16, 64);
  // softmax over t (redundant per lane; register-only)
  float mx = al[0];
#pragma unroll
  for (int t = 1; t < Tt; t++) mx = fmaxf(mx, al[t]);
  float ssum = 0.f;
#pragma unroll
  for (int t = 0; t < Tt; t++) { al[t] = expf(al[t] - mx); ssum += al[t]; }
  float inv = 1.0f / ssum;
  // context: lane owns channel o = lane; hs rows are L2-hot (just read as A-frags)
  float cx = 0.f;
#pragma unroll
  for (int t = 0; t < Tt; t++)
    cx = fmaf(al[t], __half2float(hs16[(size_t)t * Nn * Hh + (size_t)i * Hh + lane]), cx);
  float p = cx * inv * Wfc[lane];
#pragma unroll
  for (int off = 32; off >= 1; off >>= 1) p += __shfl_xor(p, off, 64);
  if (lane == 0) out[i] = p + bfc[0];
}

extern "C" void kernel_launch(void* const* d_in, const int* in_sizes, int n_in,
                              void* d_out, int out_size, void* d_ws, size_t ws_size,
                              hipStream_t stream) {
  const float* x   = (const float*)d_in[0];
  const int* ei    = (const int*)d_in[1];
  const float* ew  = (const float*)d_in[2];
  const float* Wz  = (const float*)d_in[3];
  const float* bz  = (const float*)d_in[4];
  const float* Wr  = (const float*)d_in[5];
  const float* br  = (const float*)d_in[6];
  const float* Wh  = (const float*)d_in[7];
  const float* bh  = (const float*)d_in[8];
  const float* Wa  = (const float*)d_in[9];
  const float* ba  = (const float*)d_in[10];
  const float* cv  = (const float*)d_in[11];
  const float* Wfc = (const float*)d_in[12];
  const float* bfc = (const float*)d_in[13];
  float* out = (float*)d_out;

  char* w = (char*)d_ws;
  auto alloc = [&](size_t bytes) {
    char* p = w;
    w += (bytes + 255) & ~(size_t)255;
    return p;
  };
  unsigned long long* dc = (unsigned long long*)alloc((size_t)Nn * 8);
  float* dis = (float*)alloc((size_t)Nn * 4);
  int* cnt   = (int*)alloc((size_t)Nn * 4);
  int* rp    = (int*)alloc((size_t)(Nn + 1) * 4);
  int* cur   = (int*)alloc((size_t)Nn * 4);
  int2* edge2 = (int2*)alloc((size_t)Ee * 8);
  __half* x16  = (__half*)alloc((size_t)Nn * Ff * Tt * 2);
  __half* Px16 = (__half*)alloc((size_t)Tt * Nn * Ff * 2);
  float* h     = (float*)alloc((size_t)Nn * Hh * 4);
  __half* h16  = (__half*)alloc((size_t)Nn * Hh * 2);
  __half* rh16 = (__half*)alloc((size_t)Nn * Hh * 2);
  __half* zb16 = (__half*)alloc((size_t)Nn * Hh * 2);
  __half* Ph16 = (__half*)alloc((size_t)Nn * Hh * 2);
  __half* Prh16 = (__half*)alloc((size_t)Nn * Hh * 2);
  __half* hs16 = (__half*)alloc((size_t)Tt * Nn * Hh * 2);  // 76.8 MB history
  __half* wfrag = (__half*)alloc((size_t)12 * 3 * 64 * 8 * 2);  // 36.9 KB frag weights
  __half* wfragA = (__half*)alloc((size_t)8 * 64 * 8 * 2);      // 8 KB Wa frags

  hipMemsetAsync(dc, 0, (size_t)Nn * 8, stream);
  hipMemsetAsync(h, 0, (size_t)Nn * Hh * 4, stream);
  hipMemsetAsync(h16, 0, (size_t)Nn * Hh * 2, stream);  // fp16 zero == 0x0000

  k_deg<<<(Ee + 255) / 256, 256, 0, stream>>>(ei, ew, dc);
  k_dis<<<(Nn + 255) / 256, 256, 0, stream>>>(dc, dis, cnt);
  k_scan<<<1, 1024, 0, stream>>>(cnt, rp, cur);
  k_scatter<<<(Ee + 255) / 256, 256, 0, stream>>>(ei, ew, dis, cur, edge2);
  {
    const size_t total = (size_t)Nn * Ff * Tt;
    k_cvt_x<<<(int)((total + 255) / 256), 256, 0, stream>>>(x, x16);
  }
  k_wfrag<<<9, 256, 0, stream>>>(Wz, Wr, Wh, wfrag);
  k_wfrag_a<<<2, 256, 0, stream>>>(Wa, wfragA);
  k_agg_px<<<(Nn + 3) / 4, 256, 0, stream>>>(x, x16, Px16, rp, edge2, dis);

  const int gGemm = Nn / 16;  // 3125 blocks, 16 nodes each (exact)
  const int gNode = (Nn + 3) / 4;
  for (int t = 0; t < Tt; t++) {
    k_agg64v<<<gNode, 256, 0, stream>>>(h16, Ph16, rp, edge2, dis);
    k_gemm_zr<<<gGemm, 256, 0, stream>>>(Px16, Ph16, h16, wfrag, bz, br, zb16, rh16, t);
    k_agg64v<<<gNode, 256, 0, stream>>>(rh16, Prh16, rp, edge2, dis);
    k_gemm_h<<<gGemm, 256, 0, stream>>>(Px16, Prh16, zb16, h, h16, hs16, wfrag, bh, t);
  }
  k_att<<<gNode, 256, 0, stream>>>(hs16, wfragA, ba, cv, Wfc, bfc, out);
}

// Round 2
// 1539.524 us; speedup vs baseline: 1.1648x; 1.0722x over previous
//
#include <hip/hip_runtime.h>
#include <hip/hip_fp16.h>
#include <math.h>

#define Nn 50000
#define Ff 16
#define Tt 12
#define Hh 64
#define Ee 1600000
#define Cc 80  // F + H

#define SCAN_NB 98  // ceil(50000 / 512), each block covers 512 elements

typedef _Float16 f16x8 __attribute__((ext_vector_type(8)));
typedef float f32x4 __attribute__((ext_vector_type(4)));

static __device__ __forceinline__ float sigmoidf_(float x) { return 1.0f / (1.0f + expf(-x)); }

// ---------------- CSR build ----------------
// dc[d] accumulates (count << 42) + round(ew * 2^21) in one u64 atomic.
__global__ void k_deg(const int* __restrict__ ei, const float* __restrict__ ew,
                      unsigned long long* __restrict__ dc) {
  int e = blockIdx.x * blockDim.x + threadIdx.x;
  if (e >= Ee) return;
  int d = ei[Ee + e];
  unsigned long long pk = (1ULL << 42) + (unsigned long long)(ew[e] * 2097152.0f + 0.5f);
  atomicAdd(&dc[d], pk);
}

__global__ void k_dis(const unsigned long long* __restrict__ dc,
                      float* __restrict__ dis, int* __restrict__ cnt) {
  int i = blockIdx.x * blockDim.x + threadIdx.x;
  if (i >= Nn) return;
  unsigned long long v = dc[i];
  cnt[i] = (int)(v >> 42);
  float deg = (float)(v & ((1ULL << 42) - 1)) * (1.0f / 2097152.0f);
  dis[i] = 1.0f / sqrtf(deg + 1.0f);
}

// ---- multi-block exclusive scan of cnt[Nn] -> rp/cur (replaces 126us single-block k_scan) ----
// phase 1: per-block sums (block b covers elements [b*512, b*512+512))
__global__ __launch_bounds__(256) void k_scan1(const int* __restrict__ cnt,
                                               int* __restrict__ bsum) {
  __shared__ int ss[256];
  int b = blockIdx.x, t = threadIdx.x;
  int base = b * 512 + t * 2;
  int s = 0;
  if (base < Nn) s += cnt[base];
  if (base + 1 < Nn) s += cnt[base + 1];
  ss[t] = s;
  __syncthreads();
  for (int off = 128; off > 0; off >>= 1) {
    if (t < off) ss[t] += ss[t + off];
    __syncthreads();
  }
  if (t == 0) bsum[b] = ss[0];
}

// phase 2: exclusive scan of the 98 block sums (single tiny block)
__global__ __launch_bounds__(128) void k_scan2(const int* __restrict__ bsum,
                                               int* __restrict__ boff) {
  __shared__ int ss[128];
  int t = threadIdx.x;
  int v = (t < SCAN_NB) ? bsum[t] : 0;
  ss[t] = v;
  __syncthreads();
  for (int off = 1; off < 128; off <<= 1) {
    int u = (t >= off) ? ss[t - off] : 0;
    __syncthreads();
    ss[t] += u;
    __syncthreads();
  }
  if (t < SCAN_NB) boff[t] = ss[t] - v;  // exclusive
}

// phase 3: block-local exclusive scan + block offset -> rp, cur
__global__ __launch_bounds__(256) void k_scan3(const int* __restrict__ cnt,
                                               const int* __restrict__ boff,
                                               int* __restrict__ rp, int* __restrict__ cur) {
  __shared__ int ss[256];
  int b = blockIdx.x, t = threadIdx.x;
  int base = b * 512 + t * 2;
  int c0 = (base < Nn) ? cnt[base] : 0;
  int c1 = (base + 1 < Nn) ? cnt[base + 1] : 0;
  int s = c0 + c1;
  ss[t] = s;
  __syncthreads();
  for (int off = 1; off < 256; off <<= 1) {
    int u = (t >= off) ? ss[t - off] : 0;
    __syncthreads();
    ss[t] += u;
    __syncthreads();
  }
  int run = boff[b] + ss[t] - s;  // exclusive prefix of this thread's first element
  if (base < Nn) { rp[base] = run; cur[base] = run; }
  if (base + 1 < Nn) { rp[base + 1] = run + c0; cur[base + 1] = run + c0; }
  if (b == 0 && t == 0) rp[Nn] = Ee;
}

// edge2[pos] = {src, normalized weight}: one scattered 8-B store per edge
__global__ void k_scatter(const int* __restrict__ ei, const float* __restrict__ ew,
                          const float* __restrict__ dis, int* __restrict__ cur,
                          int2* __restrict__ edge2) {
  int e = blockIdx.x * blockDim.x + threadIdx.x;
  if (e >= Ee) return;
  int s = ei[e];
  int d = ei[Ee + e];
  float w = ew[e] * dis[s] * dis[d];
  int pos = atomicAdd(&cur[d], 1);
  edge2[pos] = make_int2(s, __float_as_int(w));
}

// ---------------- x fp32 -> fp16 (once) ----------------
__global__ void k_cvt_x(const float* __restrict__ x, __half* __restrict__ x16) {
  size_t idx = (size_t)blockIdx.x * blockDim.x + threadIdx.x;
  const size_t total = (size_t)Nn * Ff * Tt;
  if (idx < total) x16[idx] = __float2half(x[idx]);
}

// ---------------- weight fragments for MFMA (once) ----------------
// slot s: 0-3 = Wz tiles, 4-7 = Wr tiles, 8-11 = Wh tiles; n0 = (s&3)*16.
// frag[((s*3+ks)*64 + lane)*8 + j] = W[k][n0 + (lane&15)], k = ks*32 + (lane>>4)*8 + j (0 if k>=80)
__global__ void k_wfrag(const float* __restrict__ Wz, const float* __restrict__ Wr,
                        const float* __restrict__ Wh, __half* __restrict__ frag) {
  int t = blockIdx.x * 256 + threadIdx.x;
  if (t >= 12 * 3 * 64) return;
  int s = t / 192, rem = t % 192, ks = rem / 64, lane = rem % 64;
  int q = lane >> 4, nl = lane & 15;
  const float* W = (s < 4) ? Wz : (s < 8) ? Wr : Wh;
  int n0 = (s & 3) * 16;
  __half tmp[8];
#pragma unroll
  for (int j = 0; j < 8; j++) {
    int k = ks * 32 + q * 8 + j;
    float v = (k < Cc) ? W[k * Hh + n0 + nl] : 0.f;
    tmp[j] = __float2half(v);
  }
  *(uint4*)(frag + ((size_t)(s * 3 + ks) * 64 + lane) * 8) = *(uint4*)tmp;
}

// Wa (64x64) fragments for attention MFMA (once).
// slot s (0..7): tile = s>>1 (n0 = tile*16), ks = s&1 (k0 = ks*32).
// fragA[(s*64 + lane)*8 + j] = Wa[k0 + (lane>>4)*8 + j][n0 + (lane&15)]
__global__ void k_wfrag_a(const float* __restrict__ Wa, __half* __restrict__ fragA) {
  int t = blockIdx.x * 256 + threadIdx.x;
  if (t >= 8 * 64) return;
  int s = t >> 6, lane = t & 63;
  int tile = s >> 1, ks = s & 1;
  int q = lane >> 4, m = lane & 15;
  __half tmp[8];
#pragma unroll
  for (int j = 0; j < 8; j++) {
    int k = ks * 32 + q * 8 + j;
    tmp[j] = __float2half(Wa[k * Hh + tile * 16 + m]);
  }
  *(uint4*)(fragA + ((size_t)t) * 8) = *(uint4*)tmp;
}

// ---------------- Px16[t][i][f] = (A_hat @ x): wave per node, 48 lanes x 8B per edge ----------------
__global__ __launch_bounds__(256) void k_agg_px(
    const float* __restrict__ x, const __half* __restrict__ x16, __half* __restrict__ Px16,
    const int* __restrict__ rp, const int2* __restrict__ edge2,
    const float* __restrict__ dis) {
  int i = blockIdx.x * 4 + (threadIdx.x >> 6);
  if (i >= Nn) return;
  int lane = threadIdx.x & 63;
  const int R = Ff * Tt;  // 192
  const bool act = lane < 48;
  float d = dis[i], sn = d * d;
  float a0 = 0.f, a1 = 0.f, a2 = 0.f, a3 = 0.f;
  if (act) {
    float4 sv = *(const float4*)(x + (size_t)i * R + 4 * lane);  // self, fp32 exact
    a0 = sn * sv.x; a1 = sn * sv.y; a2 = sn * sv.z; a3 = sn * sv.w;
  }
  int jb = rp[i], je = rp[i + 1];
  for (int j = jb; j < je; j += 2) {
    int jc1 = min(j + 1, Ee - 1);
    int2 e0 = edge2[j];
    int2 e1 = edge2[jc1];
    float w0 = __int_as_float(e0.y);
    float w1 = (j + 1 < je) ? __int_as_float(e1.y) : 0.f;
    if (act) {
      uint2 g0 = *(const uint2*)(x16 + (size_t)e0.x * R + 4 * lane);
      uint2 g1 = *(const uint2*)(x16 + (size_t)e1.x * R + 4 * lane);
      float2 p01 = __half22float2(*reinterpret_cast<const __half2*>(&g0.x));
      float2 p23 = __half22float2(*reinterpret_cast<const __half2*>(&g0.y));
      float2 q01 = __half22float2(*reinterpret_cast<const __half2*>(&g1.x));
      float2 q23 = __half22float2(*reinterpret_cast<const __half2*>(&g1.y));
      a0 = fmaf(w0, p01.x, a0); a1 = fmaf(w0, p01.y, a1);
      a2 = fmaf(w0, p23.x, a2); a3 = fmaf(w0, p23.y, a3);
      a0 = fmaf(w1, q01.x, a0); a1 = fmaf(w1, q01.y, a1);
      a2 = fmaf(w1, q23.x, a2); a3 = fmaf(w1, q23.y, a3);
    }
  }
  if (act) {
#pragma unroll
    for (int k = 0; k < 4; k++) {
      int cch = 4 * lane + k;           // channel = f*T + t
      int f = cch / Tt, tt = cch % Tt;
      float val = (k == 0) ? a0 : (k == 1) ? a1 : (k == 2) ? a2 : a3;
      Px16[(size_t)tt * Nn * Ff + (size_t)i * Ff + f] = __float2half(val);
    }
  }
}

// ---------------- aggregation: wave per node, 16 lanes/edge x 8B, 16 edges/iteration ----------------
__global__ __launch_bounds__(256) void k_agg64v(
    const __half* __restrict__ v, __half* __restrict__ outv,
    const int* __restrict__ rp, const int2* __restrict__ edge2,
    const float* __restrict__ dis) {
  int i = blockIdx.x * 4 + (threadIdx.x >> 6);
  if (i >= Nn) return;
  int lane = threadIdx.x & 63;
  int g = lane >> 4;   // edge slot 0..3
  int c = lane & 15;   // channel quad: 4c..4c+3
  float d = dis[i], sn = d * d;
  float a0, a1, a2, a3;
  {
    const uint2 gv = *(const uint2*)(v + (size_t)i * Hh + 4 * c);  // self
    float2 f01 = __half22float2(*reinterpret_cast<const __half2*>(&gv.x));
    float2 f23 = __half22float2(*reinterpret_cast<const __half2*>(&gv.y));
    float ws = (g == 0) ? sn : 0.f;
    a0 = ws * f01.x; a1 = ws * f01.y; a2 = ws * f23.x; a3 = ws * f23.y;
  }
  int jb = rp[i], je = rp[i + 1];
  for (int j0 = jb; j0 < je; j0 += 16) {
    int j1 = j0 + g;
    int j2 = j0 + 4 + g;
    int j3 = j0 + 8 + g;
    int j4 = j0 + 12 + g;
    int2 e1 = edge2[min(j1, Ee - 1)];
    int2 e2 = edge2[min(j2, Ee - 1)];
    int2 e3 = edge2[min(j3, Ee - 1)];
    int2 e4 = edge2[min(j4, Ee - 1)];
    float w1 = (j1 < je) ? __int_as_float(e1.y) : 0.f;
    float w2 = (j2 < je) ? __int_as_float(e2.y) : 0.f;
    float w3 = (j3 < je) ? __int_as_float(e3.y) : 0.f;
    float w4 = (j4 < je) ? __int_as_float(e4.y) : 0.f;
    const uint2 g1 = *(const uint2*)(v + (size_t)e1.x * Hh + 4 * c);
    const uint2 g2 = *(const uint2*)(v + (size_t)e2.x * Hh + 4 * c);
    const uint2 g3 = *(const uint2*)(v + (size_t)e3.x * Hh + 4 * c);
    const uint2 g4 = *(const uint2*)(v + (size_t)e4.x * Hh + 4 * c);
    float2 p01 = __half22float2(*reinterpret_cast<const __half2*>(&g1.x));
    float2 p23 = __half22float2(*reinterpret_cast<const __half2*>(&g1.y));
    float2 q01 = __half22float2(*reinterpret_cast<const __half2*>(&g2.x));
    float2 q23 = __half22float2(*reinterpret_cast<const __half2*>(&g2.y));
    float2 r01 = __half22float2(*reinterpret_cast<const __half2*>(&g3.x));
    float2 r23 = __half22float2(*reinterpret_cast<const __half2*>(&g3.y));
    float2 s01 = __half22float2(*reinterpret_cast<const __half2*>(&g4.x));
    float2 s23 = __half22float2(*reinterpret_cast<const __half2*>(&g4.y));
    a0 = fmaf(w1, p01.x, a0); a1 = fmaf(w1, p01.y, a1);
    a2 = fmaf(w1, p23.x, a2); a3 = fmaf(w1, p23.y, a3);
    a0 = fmaf(w2, q01.x, a0); a1 = fmaf(w2, q01.y, a1);
    a2 = fmaf(w2, q23.x, a2); a3 = fmaf(w2, q23.y, a3);
    a0 = fmaf(w3, r01.x, a0); a1 = fmaf(w3, r01.y, a1);
    a2 = fmaf(w3, r23.x, a2); a3 = fmaf(w3, r23.y, a3);
    a0 = fmaf(w4, s01.x, a0); a1 = fmaf(w4, s01.y, a1);
    a2 = fmaf(w4, s23.x, a2); a3 = fmaf(w4, s23.y, a3);
  }
  a0 += __shfl_xor(a0, 16, 64); a1 += __shfl_xor(a1, 16, 64);
  a2 += __shfl_xor(a2, 16, 64); a3 += __shfl_xor(a3, 16, 64);
  a0 += __shfl_xor(a0, 32, 64); a1 += __shfl_xor(a1, 32, 64);
  a2 += __shfl_xor(a2, 32, 64); a3 += __shfl_xor(a3, 32, 64);
  if (lane < 16) {
    __half2 h01, h23;
    h01.x = __float2half_rn(a0); h01.y = __float2half_rn(a1);
    h23.x = __float2half_rn(a2); h23.y = __float2half_rn(a3);
    uint2 st;
    st.x = *reinterpret_cast<unsigned int*>(&h01);
    st.y = *reinterpret_cast<unsigned int*>(&h23);
    *(uint2*)(outv + (size_t)i * Hh + 4 * c) = st;
  }
}

// ---- shared fp16 staging: 16 nodes x 104 halves (row = [Px(16) | P64(64) | zeros(24)]) ----
// Row stride 104 halves (208 B): a_frag ds_read_b128 lands 2 lanes/bank (free).
static __device__ __forceinline__ void stage_x16(
    __half* sX16, const __half* __restrict__ Px16t, const __half* __restrict__ P64,
    int i0, int tid) {
  if (tid < 160) {
    int n = tid / 10, r = tid % 10;
    int i = i0 + n;
    uint4 raw = (r < 2) ? *(const uint4*)(Px16t + (size_t)i * Ff + r * 8)
                        : *(const uint4*)(P64 + (size_t)i * Hh + (r - 2) * 8);
    *(uint4*)(sX16 + n * 104 + r * 8) = raw;
  } else if (tid < 208) {
    int p = tid - 160, n = p / 3, part = p % 3;
    *(uint4*)(sX16 + n * 104 + 80 + part * 8) = make_uint4(0u, 0u, 0u, 0u);
  }
}

// ---------------- GEMM z/r via MFMA 16x16x32 f16: block = 16 nodes, wave w -> out tile w ----------------
// A: X[node][c] (LDS, fp16). B: weight frags (global, pre-swizzled). K = 80 padded to 96 (3 MFMA).
// Layouts [verified per guide m89/m120]: A[m=lane&15][k=(lane>>4)*8+j]; C/D col=lane&15, row=(lane>>4)*4+reg.
// NOTE: no waves-per-EU hint (2nd __launch_bounds__ arg => scratch spill disaster, r2/r6).
__global__ __launch_bounds__(256) void k_gemm_zr(
    const __half* __restrict__ Px16, const __half* __restrict__ Ph16,
    const __half* __restrict__ h16, const __half* __restrict__ frag,
    const float* __restrict__ bz, const float* __restrict__ br,
    __half* __restrict__ zb16, __half* __restrict__ rh16, int tstep) {
  __shared__ __align__(16) __half sX16[16 * 104];
  const int tid = threadIdx.x;
  const int i0 = blockIdx.x * 16;  // Nn = 3125*16 exactly, no guards
  const int wv = tid >> 6, lane = tid & 63;
  // b-fragments: z = slot wv, r = slot 4+wv (coalesced b128 loads, L2-resident)
  f16x8 bzf[3], brf[3];
#pragma unroll
  for (int ks = 0; ks < 3; ks++) {
    bzf[ks] = *(const f16x8*)(frag + ((size_t)(wv * 3 + ks) * 64 + lane) * 8);
    brf[ks] = *(const f16x8*)(frag + ((size_t)((4 + wv) * 3 + ks) * 64 + lane) * 8);
  }
  stage_x16(sX16, Px16 + (size_t)tstep * Nn * Ff, Ph16, i0, tid);
  __syncthreads();
  const int m = lane & 15, q = lane >> 4;
  f32x4 accz = {0.f, 0.f, 0.f, 0.f}, accr = {0.f, 0.f, 0.f, 0.f};
#pragma unroll
  for (int ks = 0; ks < 3; ks++) {
    f16x8 a = *(const f16x8*)(sX16 + m * 104 + ks * 32 + q * 8);
    accz = __builtin_amdgcn_mfma_f32_16x16x32_f16(a, bzf[ks], accz, 0, 0, 0);
    accr = __builtin_amdgcn_mfma_f32_16x16x32_f16(a, brf[ks], accr, 0, 0, 0);
  }
  const int o = wv * 16 + m;
  float bzo = bz[o], bro = br[o];
  const int nb = i0 + q * 4;
#pragma unroll
  for (int r = 0; r < 4; r++) {
    int node = nb + r;
    float zv = sigmoidf_(accz[r] + bzo);
    float rv = sigmoidf_(accr[r] + bro);
    float hv = __half2float(h16[(size_t)node * Hh + o]);
    zb16[(size_t)node * Hh + o] = __float2half(zv);
    rh16[(size_t)node * Hh + o] = __float2half(rv * hv);
  }
}

// ---------------- GEMM h via MFMA + GRU update: wave w -> out tile w (slot 8+w) ----------------
__global__ __launch_bounds__(256) void k_gemm_h(
    const __half* __restrict__ Px16, const __half* __restrict__ Prh16,
    const __half* __restrict__ zb16, float* __restrict__ h, __half* __restrict__ h16,
    __half* __restrict__ hs16, const __half* __restrict__ frag,
    const float* __restrict__ bh, int tstep) {
  __shared__ __align__(16) __half sX16[16 * 104];
  const int tid = threadIdx.x;
  const int i0 = blockIdx.x * 16;
  const int wv = tid >> 6, lane = tid & 63;
  f16x8 bf[3];
#pragma unroll
  for (int ks = 0; ks < 3; ks++)
    bf[ks] = *(const f16x8*)(frag + ((size_t)((8 + wv) * 3 + ks) * 64 + lane) * 8);
  stage_x16(sX16, Px16 + (size_t)tstep * Nn * Ff, Prh16, i0, tid);
  __syncthreads();
  const int m = lane & 15, q = lane >> 4;
  f32x4 acc = {0.f, 0.f, 0.f, 0.f};
#pragma unroll
  for (int ks = 0; ks < 3; ks++) {
    f16x8 a = *(const f16x8*)(sX16 + m * 104 + ks * 32 + q * 8);
    acc = __builtin_amdgcn_mfma_f32_16x16x32_f16(a, bf[ks], acc, 0, 0, 0);
  }
  const int o = wv * 16 + m;
  float bho = bh[o];
  const int nb = i0 + q * 4;
  __half* hst = hs16 + (size_t)tstep * Nn * Hh;
#pragma unroll
  for (int r = 0; r < 4; r++) {
    int node = nb + r;
    float hc = tanhf(acc[r] + bho);
    float zv = __half2float(zb16[(size_t)node * Hh + o]);
    float hv = h[(size_t)node * Hh + o];
    float hn = zv * hv + (1.0f - zv) * hc;
    h[(size_t)node * Hh + o] = hn;
    __half hh = __float2half(hn);
    h16[(size_t)node * Hh + o] = hh;
    hst[(size_t)node * Hh + o] = hh;
  }
}

// ---------------- attention + output via MFMA: wave per node ----------------
// score = tanh(hs[12x64] @ Wa[64x64] + ba) computed with 8x mfma_f32_16x16x32_f16.
// A-frag: row m = t (m>=12 clamped to row 11, results discarded); k = ks*32 + q*8 + j.
// D layout [m89]: col o = tile*16 + (lane&15), row t = (lane>>4)*4 + r.
// No LDS at all; Wa frags pre-swizzled by k_wfrag_a (L2-resident, 8 KB).
__global__ __launch_bounds__(256) void k_att(
    const __half* __restrict__ hs16, const __half* __restrict__ fragA,
    const float* __restrict__ ba, const float* __restrict__ cv,
    const float* __restrict__ Wfc, const float* __restrict__ bfc,
    float* __restrict__ out) {
  const int tid = threadIdx.x;
  const int wv = tid >> 6, lane = tid & 63;
  const int i = blockIdx.x * 4 + wv;
  if (i >= Nn) return;
  const int m = lane & 15, q = lane >> 4;

  // B fragments: 8 slots (4 col-tiles x 2 K-steps), identical across waves -> L2 hits
  f16x8 bf[4][2];
#pragma unroll
  for (int s = 0; s < 8; s++)
    bf[s >> 1][s & 1] = *(const f16x8*)(fragA + (size_t)(s * 64 + lane) * 8);

  // A fragments: hs rows for this node (t = m, clamped; garbage rows only affect discarded D rows)
  const int tm = (m < Tt) ? m : (Tt - 1);
  const __half* hbase = hs16 + (size_t)tm * Nn * Hh + (size_t)i * Hh;
  f16x8 a0 = *(const f16x8*)(hbase + q * 8);
  f16x8 a1 = *(const f16x8*)(hbase + 32 + q * 8);

  f32x4 acc[4];
#pragma unroll
  for (int tile = 0; tile < 4; tile++) acc[tile] = f32x4{0.f, 0.f, 0.f, 0.f};
#pragma unroll
  for (int tile = 0; tile < 4; tile++) {
    acc[tile] = __builtin_amdgcn_mfma_f32_16x16x32_f16(a0, bf[tile][0], acc[tile], 0, 0, 0);
    acc[tile] = __builtin_amdgcn_mfma_f32_16x16x32_f16(a1, bf[tile][1], acc[tile], 0, 0, 0);
  }

  // epilogue: lane holds score[t = q*4+r][o = tile*16+m]
  float ba_l[4], cv_l[4];
#pragma unroll
  for (int tile = 0; tile < 4; tile++) {
    ba_l[tile] = ba[tile * 16 + m];
    cv_l[tile] = cv[tile * 16 + m];
  }
  float ar[4];
#pragma unroll
  for (int r = 0; r < 4; r++) {
    float s = 0.f;
#pragma unroll
    for (int tile = 0; tile < 4; tile++)
      s += tanhf(acc[tile][r] + ba_l[tile]) * cv_l[tile];
    // reduce over the 16 lanes of this q-group (covers all 64 o's)
    s += __shfl_xor(s, 1, 64);
    s += __shfl_xor(s, 2, 64);
    s += __shfl_xor(s, 4, 64);
    s += __shfl_xor(s, 8, 64);
    ar[r] = s;  // align[q*4 + r], valid for q*4+r < 12
  }
  // broadcast all 12 align values to every lane
  float al[Tt];
#pragma unroll
  for (int t = 0; t < Tt; t++) al[t] = __shfl(ar[t & 3], (t >> 2) * 16, 64);
  // softmax over t (redundant per lane; register-only)
  float mx = al[0];
#pragma unroll
  for (int t = 1; t < Tt; t++) mx = fmaxf(mx, al[t]);
  float ssum = 0.f;
#pragma unroll
  for (int t = 0; t < Tt; t++) { al[t] = expf(al[t] - mx); ssum += al[t]; }
  float inv = 1.0f / ssum;
  // context: lane owns channel o = lane; hs rows are L2-hot (just read as A-frags)
  float cx = 0.f;
#pragma unroll
  for (int t = 0; t < Tt; t++)
    cx = fmaf(al[t], __half2float(hs16[(size_t)t * Nn * Hh + (size_t)i * Hh + lane]), cx);
  float p = cx * inv * Wfc[lane];
#pragma unroll
  for (int off = 32; off >= 1; off >>= 1) p += __shfl_xor(p, off, 64);
  if (lane == 0) out[i] = p + bfc[0];
}

extern "C" void kernel_launch(void* const* d_in, const int* in_sizes, int n_in,
                              void* d_out, int out_size, void* d_ws, size_t ws_size,
                              hipStream_t stream) {
  const float* x   = (const float*)d_in[0];
  const int* ei    = (const int*)d_in[1];
  const float* ew  = (const float*)d_in[2];
  const float* Wz  = (const float*)d_in[3];
  const float* bz  = (const float*)d_in[4];
  const float* Wr  = (const float*)d_in[5];
  const float* br  = (const float*)d_in[6];
  const float* Wh  = (const float*)d_in[7];
  const float* bh  = (const float*)d_in[8];
  const float* Wa  = (const float*)d_in[9];
  const float* ba  = (const float*)d_in[10];
  const float* cv  = (const float*)d_in[11];
  const float* Wfc = (const float*)d_in[12];
  const float* bfc = (const float*)d_in[13];
  float* out = (float*)d_out;

  char* w = (char*)d_ws;
  auto alloc = [&](size_t bytes) {
    char* p = w;
    w += (bytes + 255) & ~(size_t)255;
    return p;
  };
  unsigned long long* dc = (unsigned long long*)alloc((size_t)Nn * 8);
  float* dis = (float*)alloc((size_t)Nn * 4);
  int* cnt   = (int*)alloc((size_t)Nn * 4);
  int* rp    = (int*)alloc((size_t)(Nn + 1) * 4);
  int* cur   = (int*)alloc((size_t)Nn * 4);
  int* bsum  = (int*)alloc((size_t)SCAN_NB * 4);
  int* boff  = (int*)alloc((size_t)SCAN_NB * 4);
  int2* edge2 = (int2*)alloc((size_t)Ee * 8);
  __half* x16  = (__half*)alloc((size_t)Nn * Ff * Tt * 2);
  __half* Px16 = (__half*)alloc((size_t)Tt * Nn * Ff * 2);
  float* h     = (float*)alloc((size_t)Nn * Hh * 4);
  __half* h16  = (__half*)alloc((size_t)Nn * Hh * 2);
  __half* rh16 = (__half*)alloc((size_t)Nn * Hh * 2);
  __half* zb16 = (__half*)alloc((size_t)Nn * Hh * 2);
  __half* Ph16 = (__half*)alloc((size_t)Nn * Hh * 2);
  __half* Prh16 = (__half*)alloc((size_t)Nn * Hh * 2);
  __half* hs16 = (__half*)alloc((size_t)Tt * Nn * Hh * 2);  // 76.8 MB history
  __half* wfrag = (__half*)alloc((size_t)12 * 3 * 64 * 8 * 2);  // 36.9 KB frag weights
  __half* wfragA = (__half*)alloc((size_t)8 * 64 * 8 * 2);      // 8 KB Wa frags

  hipMemsetAsync(dc, 0, (size_t)Nn * 8, stream);
  hipMemsetAsync(h, 0, (size_t)Nn * Hh * 4, stream);
  hipMemsetAsync(h16, 0, (size_t)Nn * Hh * 2, stream);  // fp16 zero == 0x0000

  k_deg<<<(Ee + 255) / 256, 256, 0, stream>>>(ei, ew, dc);
  k_dis<<<(Nn + 255) / 256, 256, 0, stream>>>(dc, dis, cnt);
  k_scan1<<<SCAN_NB, 256, 0, stream>>>(cnt, bsum);
  k_scan2<<<1, 128, 0, stream>>>(bsum, boff);
  k_scan3<<<SCAN_NB, 256, 0, stream>>>(cnt, boff, rp, cur);
  k_scatter<<<(Ee + 255) / 256, 256, 0, stream>>>(ei, ew, dis, cur, edge2);
  {
    const size_t total = (size_t)Nn * Ff * Tt;
    k_cvt_x<<<(int)((total + 255) / 256), 256, 0, stream>>>(x, x16);
  }
  k_wfrag<<<9, 256, 0, stream>>>(Wz, Wr, Wh, wfrag);
  k_wfrag_a<<<2, 256, 0, stream>>>(Wa, wfragA);
  k_agg_px<<<(Nn + 3) / 4, 256, 0, stream>>>(x, x16, Px16, rp, edge2, dis);

  const int gGemm = Nn / 16;  // 3125 blocks, 16 nodes each (exact)
  const int gNode = (Nn + 3) / 4;
  for (int t = 0; t < Tt; t++) {
    k_agg64v<<<gNode, 256, 0, stream>>>(h16, Ph16, rp, edge2, dis);
    k_gemm_zr<<<gGemm, 256, 0, stream>>>(Px16, Ph16, h16, wfrag, bz, br, zb16, rh16, t);
    k_agg64v<<<gNode, 256, 0, stream>>>(rh16, Prh16, rp, edge2, dis);
    k_gemm_h<<<gGemm, 256, 0, stream>>>(Px16, Prh16, zb16, h, h16, hs16, wfrag, bh, t);
  }
  k_att<<<gNode, 256, 0, stream>>>(hs16, wfragA, ba, cv, Wfc, bfc, out);
}

// Round 3
// 1516.874 us; speedup vs baseline: 1.1822x; 1.0149x over previous
//
#include <hip/hip_runtime.h>
#include <hip/hip_fp16.h>
#include <math.h>

#define Nn 50000
#define Ff 16
#define Tt 12
#define Hh 64
#define Ee 1600000
#define Cc 80  // F + H

#define SCAN_NB 98  // ceil(50000 / 512), each block covers 512 elements

typedef _Float16 f16x8 __attribute__((ext_vector_type(8)));
typedef float f32x4 __attribute__((ext_vector_type(4)));

static __device__ __forceinline__ float sigmoidf_(float x) { return 1.0f / (1.0f + expf(-x)); }

// ---------------- CSR build ----------------
// dc[d] accumulates (count << 42) + round(ew * 2^21) in one u64 atomic.
__global__ void k_deg(const int* __restrict__ ei, const float* __restrict__ ew,
                      unsigned long long* __restrict__ dc) {
  int e = blockIdx.x * blockDim.x + threadIdx.x;
  if (e >= Ee) return;
  int d = ei[Ee + e];
  unsigned long long pk = (1ULL << 42) + (unsigned long long)(ew[e] * 2097152.0f + 0.5f);
  atomicAdd(&dc[d], pk);
}

__global__ void k_dis(const unsigned long long* __restrict__ dc,
                      float* __restrict__ dis, int* __restrict__ cnt) {
  int i = blockIdx.x * blockDim.x + threadIdx.x;
  if (i >= Nn) return;
  unsigned long long v = dc[i];
  cnt[i] = (int)(v >> 42);
  float deg = (float)(v & ((1ULL << 42) - 1)) * (1.0f / 2097152.0f);
  dis[i] = 1.0f / sqrtf(deg + 1.0f);
}

// ---- multi-block exclusive scan of cnt[Nn] -> rp/cur ----
__global__ __launch_bounds__(256) void k_scan1(const int* __restrict__ cnt,
                                               int* __restrict__ bsum) {
  __shared__ int ss[256];
  int b = blockIdx.x, t = threadIdx.x;
  int base = b * 512 + t * 2;
  int s = 0;
  if (base < Nn) s += cnt[base];
  if (base + 1 < Nn) s += cnt[base + 1];
  ss[t] = s;
  __syncthreads();
  for (int off = 128; off > 0; off >>= 1) {
    if (t < off) ss[t] += ss[t + off];
    __syncthreads();
  }
  if (t == 0) bsum[b] = ss[0];
}

__global__ __launch_bounds__(128) void k_scan2(const int* __restrict__ bsum,
                                               int* __restrict__ boff) {
  __shared__ int ss[128];
  int t = threadIdx.x;
  int v = (t < SCAN_NB) ? bsum[t] : 0;
  ss[t] = v;
  __syncthreads();
  for (int off = 1; off < 128; off <<= 1) {
    int u = (t >= off) ? ss[t - off] : 0;
    __syncthreads();
    ss[t] += u;
    __syncthreads();
  }
  if (t < SCAN_NB) boff[t] = ss[t] - v;  // exclusive
}

__global__ __launch_bounds__(256) void k_scan3(const int* __restrict__ cnt,
                                               const int* __restrict__ boff,
                                               int* __restrict__ rp, int* __restrict__ cur) {
  __shared__ int ss[256];
  int b = blockIdx.x, t = threadIdx.x;
  int base = b * 512 + t * 2;
  int c0 = (base < Nn) ? cnt[base] : 0;
  int c1 = (base + 1 < Nn) ? cnt[base + 1] : 0;
  int s = c0 + c1;
  ss[t] = s;
  __syncthreads();
  for (int off = 1; off < 256; off <<= 1) {
    int u = (t >= off) ? ss[t - off] : 0;
    __syncthreads();
    ss[t] += u;
    __syncthreads();
  }
  int run = boff[b] + ss[t] - s;
  if (base < Nn) { rp[base] = run; cur[base] = run; }
  if (base + 1 < Nn) { rp[base + 1] = run + c0; cur[base + 1] = run + c0; }
  if (b == 0 && t == 0) rp[Nn] = Ee;
}

// edge2[pos] = {src, normalized weight}: one scattered 8-B store per edge
__global__ void k_scatter(const int* __restrict__ ei, const float* __restrict__ ew,
                          const float* __restrict__ dis, int* __restrict__ cur,
                          int2* __restrict__ edge2) {
  int e = blockIdx.x * blockDim.x + threadIdx.x;
  if (e >= Ee) return;
  int s = ei[e];
  int d = ei[Ee + e];
  float w = ew[e] * dis[s] * dis[d];
  int pos = atomicAdd(&cur[d], 1);
  edge2[pos] = make_int2(s, __float_as_int(w));
}

// ---------------- x fp32 -> fp16 (once) ----------------
__global__ void k_cvt_x(const float* __restrict__ x, __half* __restrict__ x16) {
  size_t idx = (size_t)blockIdx.x * blockDim.x + threadIdx.x;
  const size_t total = (size_t)Nn * Ff * Tt;
  if (idx < total) x16[idx] = __float2half(x[idx]);
}

// ---------------- weight fragments for MFMA (once) ----------------
// slot s: 0-3 = Wz tiles, 4-7 = Wr tiles, 8-11 = Wh tiles; n0 = (s&3)*16.
__global__ void k_wfrag(const float* __restrict__ Wz, const float* __restrict__ Wr,
                        const float* __restrict__ Wh, __half* __restrict__ frag) {
  int t = blockIdx.x * 256 + threadIdx.x;
  if (t >= 12 * 3 * 64) return;
  int s = t / 192, rem = t % 192, ks = rem / 64, lane = rem % 64;
  int q = lane >> 4, nl = lane & 15;
  const float* W = (s < 4) ? Wz : (s < 8) ? Wr : Wh;
  int n0 = (s & 3) * 16;
  __half tmp[8];
#pragma unroll
  for (int j = 0; j < 8; j++) {
    int k = ks * 32 + q * 8 + j;
    float v = (k < Cc) ? W[k * Hh + n0 + nl] : 0.f;
    tmp[j] = __float2half(v);
  }
  *(uint4*)(frag + ((size_t)(s * 3 + ks) * 64 + lane) * 8) = *(uint4*)tmp;
}

// Wa (64x64) fragments for attention MFMA (once).
__global__ void k_wfrag_a(const float* __restrict__ Wa, __half* __restrict__ fragA) {
  int t = blockIdx.x * 256 + threadIdx.x;
  if (t >= 8 * 64) return;
  int s = t >> 6, lane = t & 63;
  int tile = s >> 1, ks = s & 1;
  int q = lane >> 4, m = lane & 15;
  __half tmp[8];
#pragma unroll
  for (int j = 0; j < 8; j++) {
    int k = ks * 32 + q * 8 + j;
    tmp[j] = __float2half(Wa[k * Hh + tile * 16 + m]);
  }
  *(uint4*)(fragA + ((size_t)t) * 8) = *(uint4*)tmp;
}

// ---------------- Px16[t][i][f] = (A_hat @ x): wave per node, 48 lanes x 8B per edge ----------------
__global__ __launch_bounds__(256) void k_agg_px(
    const float* __restrict__ x, const __half* __restrict__ x16, __half* __restrict__ Px16,
    const int* __restrict__ rp, const int2* __restrict__ edge2,
    const float* __restrict__ dis) {
  int i = blockIdx.x * 4 + (threadIdx.x >> 6);
  if (i >= Nn) return;
  int lane = threadIdx.x & 63;
  const int R = Ff * Tt;  // 192
  const bool act = lane < 48;
  float d = dis[i], sn = d * d;
  float a0 = 0.f, a1 = 0.f, a2 = 0.f, a3 = 0.f;
  if (act) {
    float4 sv = *(const float4*)(x + (size_t)i * R + 4 * lane);  // self, fp32 exact
    a0 = sn * sv.x; a1 = sn * sv.y; a2 = sn * sv.z; a3 = sn * sv.w;
  }
  int jb = rp[i], je = rp[i + 1];
  for (int j = jb; j < je; j += 2) {
    int jc1 = min(j + 1, Ee - 1);
    int2 e0 = edge2[j];
    int2 e1 = edge2[jc1];
    float w0 = __int_as_float(e0.y);
    float w1 = (j + 1 < je) ? __int_as_float(e1.y) : 0.f;
    if (act) {
      uint2 g0 = *(const uint2*)(x16 + (size_t)e0.x * R + 4 * lane);
      uint2 g1 = *(const uint2*)(x16 + (size_t)e1.x * R + 4 * lane);
      float2 p01 = __half22float2(*reinterpret_cast<const __half2*>(&g0.x));
      float2 p23 = __half22float2(*reinterpret_cast<const __half2*>(&g0.y));
      float2 q01 = __half22float2(*reinterpret_cast<const __half2*>(&g1.x));
      float2 q23 = __half22float2(*reinterpret_cast<const __half2*>(&g1.y));
      a0 = fmaf(w0, p01.x, a0); a1 = fmaf(w0, p01.y, a1);
      a2 = fmaf(w0, p23.x, a2); a3 = fmaf(w0, p23.y, a3);
      a0 = fmaf(w1, q01.x, a0); a1 = fmaf(w1, q01.y, a1);
      a2 = fmaf(w1, q23.x, a2); a3 = fmaf(w1, q23.y, a3);
    }
  }
  if (act) {
#pragma unroll
    for (int k = 0; k < 4; k++) {
      int cch = 4 * lane + k;           // channel = f*T + t
      int f = cch / Tt, tt = cch % Tt;
      float val = (k == 0) ? a0 : (k == 1) ? a1 : (k == 2) ? a2 : a3;
      Px16[(size_t)tt * Nn * Ff + (size_t)i * Ff + f] = __float2half(val);
    }
  }
}

// ---- fused helpers ----
// Stage Px rows (halves [0,16)) and zero tail (halves [80,104)) for 16 nodes.
static __device__ __forceinline__ void stage_px_zero(
    __half* sX16, const __half* __restrict__ Px16t, int i0, int tid) {
  if (tid < 32) {
    int n = tid >> 1, r = tid & 1;
    *(uint4*)(sX16 + n * 104 + r * 8) =
        *(const uint4*)(Px16t + (size_t)(i0 + n) * Ff + r * 8);
  } else if (tid < 80) {
    int p = tid - 32, n = p / 3, part = p % 3;
    *(uint4*)(sX16 + n * 104 + 80 + part * 8) = make_uint4(0u, 0u, 0u, 0u);
  }
}

// Aggregate A_hat @ v for node i with one full wave (16 lanes/edge x 4 edge slots),
// write 64 fp16 channels into sX16 row `n` at half-offset 16. Same math as old k_agg64v.
static __device__ __forceinline__ void agg_node_to_lds(
    __half* sX16, int n, int i, int lane,
    const __half* __restrict__ v, const int* __restrict__ rp,
    const int2* __restrict__ edge2, const float* __restrict__ dis) {
  int g = lane >> 4;   // edge slot 0..3
  int c = lane & 15;   // channel quad: 4c..4c+3
  float d = dis[i], sn = d * d;
  float a0, a1, a2, a3;
  {
    const uint2 gv = *(const uint2*)(v + (size_t)i * Hh + 4 * c);  // self
    float2 f01 = __half22float2(*reinterpret_cast<const __half2*>(&gv.x));
    float2 f23 = __half22float2(*reinterpret_cast<const __half2*>(&gv.y));
    float ws = (g == 0) ? sn : 0.f;
    a0 = ws * f01.x; a1 = ws * f01.y; a2 = ws * f23.x; a3 = ws * f23.y;
  }
  int jb = rp[i], je = rp[i + 1];
  for (int j0 = jb; j0 < je; j0 += 16) {
    int j1 = j0 + g;
    int j2 = j0 + 4 + g;
    int j3 = j0 + 8 + g;
    int j4 = j0 + 12 + g;
    int2 e1 = edge2[min(j1, Ee - 1)];
    int2 e2 = edge2[min(j2, Ee - 1)];
    int2 e3 = edge2[min(j3, Ee - 1)];
    int2 e4 = edge2[min(j4, Ee - 1)];
    float w1 = (j1 < je) ? __int_as_float(e1.y) : 0.f;
    float w2 = (j2 < je) ? __int_as_float(e2.y) : 0.f;
    float w3 = (j3 < je) ? __int_as_float(e3.y) : 0.f;
    float w4 = (j4 < je) ? __int_as_float(e4.y) : 0.f;
    const uint2 g1 = *(const uint2*)(v + (size_t)e1.x * Hh + 4 * c);
    const uint2 g2 = *(const uint2*)(v + (size_t)e2.x * Hh + 4 * c);
    const uint2 g3 = *(const uint2*)(v + (size_t)e3.x * Hh + 4 * c);
    const uint2 g4 = *(const uint2*)(v + (size_t)e4.x * Hh + 4 * c);
    float2 p01 = __half22float2(*reinterpret_cast<const __half2*>(&g1.x));
    float2 p23 = __half22float2(*reinterpret_cast<const __half2*>(&g1.y));
    float2 q01 = __half22float2(*reinterpret_cast<const __half2*>(&g2.x));
    float2 q23 = __half22float2(*reinterpret_cast<const __half2*>(&g2.y));
    float2 r01 = __half22float2(*reinterpret_cast<const __half2*>(&g3.x));
    float2 r23 = __half22float2(*reinterpret_cast<const __half2*>(&g3.y));
    float2 s01 = __half22float2(*reinterpret_cast<const __half2*>(&g4.x));
    float2 s23 = __half22float2(*reinterpret_cast<const __half2*>(&g4.y));
    a0 = fmaf(w1, p01.x, a0); a1 = fmaf(w1, p01.y, a1);
    a2 = fmaf(w1, p23.x, a2); a3 = fmaf(w1, p23.y, a3);
    a0 = fmaf(w2, q01.x, a0); a1 = fmaf(w2, q01.y, a1);
    a2 = fmaf(w2, q23.x, a2); a3 = fmaf(w2, q23.y, a3);
    a0 = fmaf(w3, r01.x, a0); a1 = fmaf(w3, r01.y, a1);
    a2 = fmaf(w3, r23.x, a2); a3 = fmaf(w3, r23.y, a3);
    a0 = fmaf(w4, s01.x, a0); a1 = fmaf(w4, s01.y, a1);
    a2 = fmaf(w4, s23.x, a2); a3 = fmaf(w4, s23.y, a3);
  }
  a0 += __shfl_xor(a0, 16, 64); a1 += __shfl_xor(a1, 16, 64);
  a2 += __shfl_xor(a2, 16, 64); a3 += __shfl_xor(a3, 16, 64);
  a0 += __shfl_xor(a0, 32, 64); a1 += __shfl_xor(a1, 32, 64);
  a2 += __shfl_xor(a2, 32, 64); a3 += __shfl_xor(a3, 32, 64);
  if (lane < 16) {
    __half2 h01, h23;
    h01.x = __float2half_rn(a0); h01.y = __float2half_rn(a1);
    h23.x = __float2half_rn(a2); h23.y = __float2half_rn(a3);
    uint2 st;
    st.x = *reinterpret_cast<unsigned int*>(&h01);
    st.y = *reinterpret_cast<unsigned int*>(&h23);
    *(uint2*)(sX16 + n * 104 + 16 + 4 * c) = st;  // 16 lanes x 8B contiguous: 2 lanes/bank, free
  }
}

// ---------------- FUSED agg(h16) + GEMM z/r ----------------
// Block = 16 nodes, 4 waves. Wave wv aggregates nodes i0+wv*4..+3 into LDS, then
// computes out tile wv via MFMA (same layout as before). Removes Ph16 round-trip.
__global__ __launch_bounds__(256) void k_zr_f(
    const __half* __restrict__ Px16, const __half* __restrict__ h16,
    const __half* __restrict__ frag,
    const float* __restrict__ bz, const float* __restrict__ br,
    const int* __restrict__ rp, const int2* __restrict__ edge2,
    const float* __restrict__ dis,
    __half* __restrict__ zb16, __half* __restrict__ rh16, int tstep) {
  __shared__ __align__(16) __half sX16[16 * 104];
  const int tid = threadIdx.x;
  const int i0 = blockIdx.x * 16;  // Nn = 3125*16 exactly
  const int wv = tid >> 6, lane = tid & 63;
  f16x8 bzf[3], brf[3];
#pragma unroll
  for (int ks = 0; ks < 3; ks++) {
    bzf[ks] = *(const f16x8*)(frag + ((size_t)(wv * 3 + ks) * 64 + lane) * 8);
    brf[ks] = *(const f16x8*)(frag + ((size_t)((4 + wv) * 3 + ks) * 64 + lane) * 8);
  }
  stage_px_zero(sX16, Px16 + (size_t)tstep * Nn * Ff, i0, tid);
#pragma unroll
  for (int k = 0; k < 4; k++) {
    int n = wv * 4 + k;
    agg_node_to_lds(sX16, n, i0 + n, lane, h16, rp, edge2, dis);
  }
  __syncthreads();
  const int m = lane & 15, q = lane >> 4;
  f32x4 accz = {0.f, 0.f, 0.f, 0.f}, accr = {0.f, 0.f, 0.f, 0.f};
#pragma unroll
  for (int ks = 0; ks < 3; ks++) {
    f16x8 a = *(const f16x8*)(sX16 + m * 104 + ks * 32 + q * 8);
    accz = __builtin_amdgcn_mfma_f32_16x16x32_f16(a, bzf[ks], accz, 0, 0, 0);
    accr = __builtin_amdgcn_mfma_f32_16x16x32_f16(a, brf[ks], accr, 0, 0, 0);
  }
  const int o = wv * 16 + m;
  float bzo = bz[o], bro = br[o];
  const int nb = i0 + q * 4;
#pragma unroll
  for (int r = 0; r < 4; r++) {
    int node = nb + r;
    float zv = sigmoidf_(accz[r] + bzo);
    float rv = sigmoidf_(accr[r] + bro);
    float hv = __half2float(h16[(size_t)node * Hh + o]);
    zb16[(size_t)node * Hh + o] = __float2half(zv);
    rh16[(size_t)node * Hh + o] = __float2half(rv * hv);
  }
}

// ---------------- FUSED agg(rh16) + GEMM h + GRU update ----------------
__global__ __launch_bounds__(256) void k_h_f(
    const __half* __restrict__ Px16, const __half* __restrict__ rh16,
    const __half* __restrict__ zb16, float* __restrict__ h, __half* __restrict__ h16,
    __half* __restrict__ hs16, const __half* __restrict__ frag,
    const float* __restrict__ bh,
    const int* __restrict__ rp, const int2* __restrict__ edge2,
    const float* __restrict__ dis, int tstep) {
  __shared__ __align__(16) __half sX16[16 * 104];
  const int tid = threadIdx.x;
  const int i0 = blockIdx.x * 16;
  const int wv = tid >> 6, lane = tid & 63;
  f16x8 bf[3];
#pragma unroll
  for (int ks = 0; ks < 3; ks++)
    bf[ks] = *(const f16x8*)(frag + ((size_t)((8 + wv) * 3 + ks) * 64 + lane) * 8);
  stage_px_zero(sX16, Px16 + (size_t)tstep * Nn * Ff, i0, tid);
#pragma unroll
  for (int k = 0; k < 4; k++) {
    int n = wv * 4 + k;
    agg_node_to_lds(sX16, n, i0 + n, lane, rh16, rp, edge2, dis);
  }
  __syncthreads();
  const int m = lane & 15, q = lane >> 4;
  f32x4 acc = {0.f, 0.f, 0.f, 0.f};
#pragma unroll
  for (int ks = 0; ks < 3; ks++) {
    f16x8 a = *(const f16x8*)(sX16 + m * 104 + ks * 32 + q * 8);
    acc = __builtin_amdgcn_mfma_f32_16x16x32_f16(a, bf[ks], acc, 0, 0, 0);
  }
  const int o = wv * 16 + m;
  float bho = bh[o];
  const int nb = i0 + q * 4;
  __half* hst = hs16 + (size_t)tstep * Nn * Hh;
#pragma unroll
  for (int r = 0; r < 4; r++) {
    int node = nb + r;
    float hc = tanhf(acc[r] + bho);
    float zv = __half2float(zb16[(size_t)node * Hh + o]);
    float hv = h[(size_t)node * Hh + o];
    float hn = zv * hv + (1.0f - zv) * hc;
    h[(size_t)node * Hh + o] = hn;
    __half hh = __float2half(hn);
    h16[(size_t)node * Hh + o] = hh;
    hst[(size_t)node * Hh + o] = hh;
  }
}

// ---------------- attention + output via MFMA: wave per node ----------------
__global__ __launch_bounds__(256) void k_att(
    const __half* __restrict__ hs16, const __half* __restrict__ fragA,
    const float* __restrict__ ba, const float* __restrict__ cv,
    const float* __restrict__ Wfc, const float* __restrict__ bfc,
    float* __restrict__ out) {
  const int tid = threadIdx.x;
  const int wv = tid >> 6, lane = tid & 63;
  const int i = blockIdx.x * 4 + wv;
  if (i >= Nn) return;
  const int m = lane & 15, q = lane >> 4;

  f16x8 bf[4][2];
#pragma unroll
  for (int s = 0; s < 8; s++)
    bf[s >> 1][s & 1] = *(const f16x8*)(fragA + (size_t)(s * 64 + lane) * 8);

  const int tm = (m < Tt) ? m : (Tt - 1);
  const __half* hbase = hs16 + (size_t)tm * Nn * Hh + (size_t)i * Hh;
  f16x8 a0 = *(const f16x8*)(hbase + q * 8);
  f16x8 a1 = *(const f16x8*)(hbase + 32 + q * 8);

  f32x4 acc[4];
#pragma unroll
  for (int tile = 0; tile < 4; tile++) acc[tile] = f32x4{0.f, 0.f, 0.f, 0.f};
#pragma unroll
  for (int tile = 0; tile < 4; tile++) {
    acc[tile] = __builtin_amdgcn_mfma_f32_16x16x32_f16(a0, bf[tile][0], acc[tile], 0, 0, 0);
    acc[tile] = __builtin_amdgcn_mfma_f32_16x16x32_f16(a1, bf[tile][1], acc[tile], 0, 0, 0);
  }

  float ba_l[4], cv_l[4];
#pragma unroll
  for (int tile = 0; tile < 4; tile++) {
    ba_l[tile] = ba[tile * 16 + m];
    cv_l[tile] = cv[tile * 16 + m];
  }
  float ar[4];
#pragma unroll
  for (int r = 0; r < 4; r++) {
    float s = 0.f;
#pragma unroll
    for (int tile = 0; tile < 4; tile++)
      s += tanhf(acc[tile][r] + ba_l[tile]) * cv_l[tile];
    s += __shfl_xor(s, 1, 64);
    s += __shfl_xor(s, 2, 64);
    s += __shfl_xor(s, 4, 64);
    s += __shfl_xor(s, 8, 64);
    ar[r] = s;
  }
  float al[Tt];
#pragma unroll
  for (int t = 0; t < Tt; t++) al[t] = __shfl(ar[t & 3], (t >> 2) * 16, 64);
  float mx = al[0];
#pragma unroll
  for (int t = 1; t < Tt; t++) mx = fmaxf(mx, al[t]);
  float ssum = 0.f;
#pragma unroll
  for (int t = 0; t < Tt; t++) { al[t] = expf(al[t] - mx); ssum += al[t]; }
  float inv = 1.0f / ssum;
  float cx = 0.f;
#pragma unroll
  for (int t = 0; t < Tt; t++)
    cx = fmaf(al[t], __half2float(hs16[(size_t)t * Nn * Hh + (size_t)i * Hh + lane]), cx);
  float p = cx * inv * Wfc[lane];
#pragma unroll
  for (int off = 32; off >= 1; off >>= 1) p += __shfl_xor(p, off, 64);
  if (lane == 0) out[i] = p + bfc[0];
}

extern "C" void kernel_launch(void* const* d_in, const int* in_sizes, int n_in,
                              void* d_out, int out_size, void* d_ws, size_t ws_size,
                              hipStream_t stream) {
  const float* x   = (const float*)d_in[0];
  const int* ei    = (const int*)d_in[1];
  const float* ew  = (const float*)d_in[2];
  const float* Wz  = (const float*)d_in[3];
  const float* bz  = (const float*)d_in[4];
  const float* Wr  = (const float*)d_in[5];
  const float* br  = (const float*)d_in[6];
  const float* Wh  = (const float*)d_in[7];
  const float* bh  = (const float*)d_in[8];
  const float* Wa  = (const float*)d_in[9];
  const float* ba  = (const float*)d_in[10];
  const float* cv  = (const float*)d_in[11];
  const float* Wfc = (const float*)d_in[12];
  const float* bfc = (const float*)d_in[13];
  float* out = (float*)d_out;

  char* w = (char*)d_ws;
  auto alloc = [&](size_t bytes) {
    char* p = w;
    w += (bytes + 255) & ~(size_t)255;
    return p;
  };
  unsigned long long* dc = (unsigned long long*)alloc((size_t)Nn * 8);
  float* dis = (float*)alloc((size_t)Nn * 4);
  int* cnt   = (int*)alloc((size_t)Nn * 4);
  int* rp    = (int*)alloc((size_t)(Nn + 1) * 4);
  int* cur   = (int*)alloc((size_t)Nn * 4);
  int* bsum  = (int*)alloc((size_t)SCAN_NB * 4);
  int* boff  = (int*)alloc((size_t)SCAN_NB * 4);
  int2* edge2 = (int2*)alloc((size_t)Ee * 8);
  __half* x16  = (__half*)alloc((size_t)Nn * Ff * Tt * 2);
  __half* Px16 = (__half*)alloc((size_t)Tt * Nn * Ff * 2);
  float* h     = (float*)alloc((size_t)Nn * Hh * 4);
  __half* h16  = (__half*)alloc((size_t)Nn * Hh * 2);
  __half* rh16 = (__half*)alloc((size_t)Nn * Hh * 2);
  __half* zb16 = (__half*)alloc((size_t)Nn * Hh * 2);
  __half* hs16 = (__half*)alloc((size_t)Tt * Nn * Hh * 2);  // 76.8 MB history
  __half* wfrag = (__half*)alloc((size_t)12 * 3 * 64 * 8 * 2);  // 36.9 KB frag weights
  __half* wfragA = (__half*)alloc((size_t)8 * 64 * 8 * 2);      // 8 KB Wa frags

  hipMemsetAsync(dc, 0, (size_t)Nn * 8, stream);
  hipMemsetAsync(h, 0, (size_t)Nn * Hh * 4, stream);
  hipMemsetAsync(h16, 0, (size_t)Nn * Hh * 2, stream);  // fp16 zero == 0x0000

  k_deg<<<(Ee + 255) / 256, 256, 0, stream>>>(ei, ew, dc);
  k_dis<<<(Nn + 255) / 256, 256, 0, stream>>>(dc, dis, cnt);
  k_scan1<<<SCAN_NB, 256, 0, stream>>>(cnt, bsum);
  k_scan2<<<1, 128, 0, stream>>>(bsum, boff);
  k_scan3<<<SCAN_NB, 256, 0, stream>>>(cnt, boff, rp, cur);
  k_scatter<<<(Ee + 255) / 256, 256, 0, stream>>>(ei, ew, dis, cur, edge2);
  {
    const size_t total = (size_t)Nn * Ff * Tt;
    k_cvt_x<<<(int)((total + 255) / 256), 256, 0, stream>>>(x, x16);
  }
  k_wfrag<<<9, 256, 0, stream>>>(Wz, Wr, Wh, wfrag);
  k_wfrag_a<<<2, 256, 0, stream>>>(Wa, wfragA);
  k_agg_px<<<(Nn + 3) / 4, 256, 0, stream>>>(x, x16, Px16, rp, edge2, dis);

  const int gGemm = Nn / 16;  // 3125 blocks, 16 nodes each (exact)
  const int gNode = (Nn + 3) / 4;
  for (int t = 0; t < Tt; t++) {
    k_zr_f<<<gGemm, 256, 0, stream>>>(Px16, h16, wfrag, bz, br, rp, edge2, dis,
                                      zb16, rh16, t);
    k_h_f<<<gGemm, 256, 0, stream>>>(Px16, rh16, zb16, h, h16, hs16, wfrag, bh,
                                     rp, edge2, dis, t);
  }
  k_att<<<gNode, 256, 0, stream>>>(hs16, wfragA, ba, cv, Wfc, bfc, out);
}